// Round 11
// baseline (4602.239 us; speedup 1.0000x reference)
//
#include <hip/hip_runtime.h>
#include <hip/hip_bf16.h>

// EA-LSTM for MI355X (gfx950), round 11: single fused persistent kernel.
// B=128, T=2048, DYN=8, STAT=24, H=256, OUT=1.
// 32 WGs x 256 thr (4 waves, 1 wave/SIMD, 512-reg unified budget). WG owns 4
// batch rows staged at A-rows {0,4,8,12} so MFMA D r==0 gives one gate-set per
// (lane,nt). Wave w owns ch [w*64,(w+1)*64) of every gate.
// K=288 = 8 h-K-steps + 1 x-K-step (A cols 256..287 = x_t; dyn 0..7, stat 8..31).
// Registers: f,g all 8 ks + o ks0..5  (88 frags = 352 regs) + 16 accs.
// LDS: o ks6..7 (8 frags/wave) + x-step frags f,g,o,i (16 frags/wave) + A dbuf.
// MFMA/wave/step = 112 (~2170 cyc/SIMD issue = the floor);
// LDS reads/step = 33 b128/wave (~1580 cyc/CU, hidden under MFMA).
// One barrier per step. No workspace, no precompute pass.

#define T_LEN 2048
#define HD 256

typedef __attribute__((ext_vector_type(8))) short bf16x8;
typedef __attribute__((ext_vector_type(4))) float f32x4;

#define LOG2E 1.4426950408889634f

__device__ __forceinline__ short f2bf(float f) {
  unsigned u = __float_as_uint(f);
  unsigned r = (u + 0x7fffu + ((u >> 16) & 1u)) >> 16;
  return (short)r;
}

__device__ __forceinline__ bf16x8 loadw8(const float* p) {
  bf16x8 r;
#pragma unroll
  for (int i = 0; i < 8; ++i) r[i] = f2bf(p[i]);
  return r;
}

__device__ __forceinline__ float sigm(float x) {
  float e = __builtin_amdgcn_exp2f(-LOG2E * x);
  return __builtin_amdgcn_rcpf(1.0f + e);
}

// clamp-free tanh: 1 - 2/(e^{2x}+1); saturates to +/-1, NaN-free.
__device__ __forceinline__ float tanh_(float x) {
  float e = __builtin_amdgcn_exp2f((2.0f * LOG2E) * x);
  return 1.0f - 2.0f * __builtin_amdgcn_rcpf(e + 1.0f);
}

// A tile: 16 rows x 296 cols bf16 (0..255 = h, 256..287 = x_t, 288+ pad).
// Valid batch rows at A-rows {0,4,8,12}; other rows stay zero.
#define ASTR 296
#define ABUF (16 * ASTR)

__global__ __launch_bounds__(256, 1) void ealstm_fused(
    const float* __restrict__ x, const float* __restrict__ c0, const float* __restrict__ h0,
    const float* __restrict__ Wi, const float* __restrict__ bi,
    const float* __restrict__ Wfx, const float* __restrict__ bfx,
    const float* __restrict__ Wfh, const float* __restrict__ bfh,
    const float* __restrict__ Wgx, const float* __restrict__ bgx,
    const float* __restrict__ Wgh, const float* __restrict__ bgh,
    const float* __restrict__ Wox, const float* __restrict__ box_,
    const float* __restrict__ Woh, const float* __restrict__ boh,
    const float* __restrict__ Wout, const float* __restrict__ bout,
    float* __restrict__ out)
{
  __shared__ __attribute__((aligned(16))) short A_sh[2 * ABUF];        // 18944 B
  __shared__ __attribute__((aligned(16))) short Bx_sh[4 * 16 * 512];   // 65536 B
  __shared__ __attribute__((aligned(16))) short Bo2_sh[4 * 8 * 512];   // 32768 B
  __shared__ float out_part[2][4][4];                                  // 128 B

  const int tid = threadIdx.x;
  const int w   = tid >> 6;   // wave 0..3, owns ch [w*64, w*64+64)
  const int l   = tid & 63;
  const int lr  = l & 15;
  const int lg  = l >> 4;     // activation row = lg (A-row trick)
  const int wg  = blockIdx.x; // 4-row batch block

  // ---- register-resident weights: f,g ks0..7; o ks0..5 ----
  bf16x8 Bf[8][4], Bg[8][4], Bo[6][4];
#pragma unroll
  for (int ks = 0; ks < 8; ++ks) {
#pragma unroll
    for (int nt = 0; nt < 4; ++nt) {
      const int n = w * 64 + nt * 16 + lr;
      const int k = ks * 32 + lg * 8;
      Bf[ks][nt] = loadw8(Wfh + n * HD + k);
      Bg[ks][nt] = loadw8(Wgh + n * HD + k);
      if (ks < 6) Bo[ks][nt] = loadw8(Woh + n * HD + k);
    }
  }

  // ---- LDS-resident: o ks6..7 + x-step frags (f,g,o,i) ----
  short* bo2 = Bo2_sh + w * (8 * 512);
#pragma unroll
  for (int ks = 6; ks < 8; ++ks) {
#pragma unroll
    for (int nt = 0; nt < 4; ++nt) {
      const int n = w * 64 + nt * 16 + lr;
      bf16x8 fr = loadw8(Woh + n * HD + ks * 32 + lg * 8);
      *reinterpret_cast<bf16x8*>(bo2 + ((ks - 6) * 4 + nt) * 512 + l * 8) = fr;
    }
  }
  short* bxw = Bx_sh + w * (16 * 512);
  {
    bf16x8 z = (bf16x8)(short)0;
    const float* WxArr[3] = {Wfx, Wgx, Wox};
#pragma unroll
    for (int nt = 0; nt < 4; ++nt) {
      const int n = w * 64 + nt * 16 + lr;
#pragma unroll
      for (int g = 0; g < 3; ++g) {
        bf16x8 fr = (lg == 0) ? loadw8(WxArr[g] + n * 8) : z;
        *reinterpret_cast<bf16x8*>(bxw + (g * 4 + nt) * 512 + l * 8) = fr;
      }
      bf16x8 fi = (lg >= 1) ? loadw8(Wi + n * 24 + (lg - 1) * 8) : z;
      *reinterpret_cast<bf16x8*>(bxw + (12 + nt) * 512 + l * 8) = fi;
    }
  }

  // ---- biases, Wout, c-state ----
  float bias[4][4], woutv[4], cst[4];
#pragma unroll
  for (int nt = 0; nt < 4; ++nt) {
    const int n = w * 64 + nt * 16 + lr;
    bias[0][nt] = bfx[n] + bfh[n];
    bias[1][nt] = bgx[n] + bgh[n];
    bias[2][nt] = box_[n] + boh[n];
    bias[3][nt] = bi[n];
    woutv[nt] = Wout[n];
    cst[nt]   = c0[n];
  }
  const float boutv = bout[0];

  // ---- zero both A buffers; stage h0 at A-rows {0,4,8,12} and x_0 ----
  for (int idx = tid; idx < 2 * ABUF; idx += 256) A_sh[idx] = 0;
  __syncthreads();
  for (int idx = tid; idx < 4 * 256; idx += 256) {
    A_sh[(4 * (idx >> 8)) * ASTR + (idx & 255)] = f2bf(h0[idx & 255]);
  }
  if (tid < 128) {
    const int row = tid >> 5, k = tid & 31;
    A_sh[(4 * row) * ASTR + 256 + k] = f2bf(x[((size_t)(wg * 4 + row) * T_LEN) * 32 + k]);
  }
  __syncthreads();

  const float* xp = x + (size_t)(wg * 4 + ((tid >> 5) & 3)) * T_LEN * 32 + (tid & 31);
  const int akoff = lg * 8;
  const f32x4 z4 = {0.f, 0.f, 0.f, 0.f};

#pragma unroll 2
  for (int t = 0; t < T_LEN; ++t) {
    const int cur = t & 1;
    const short* ArowC = A_sh + cur * ABUF + lr * ASTR;
    short* Anxt = A_sh + (cur ^ 1) * ABUF;

    // finalize previous step's output (hidden under this step's MFMA phase)
    if (t > 0 && w == 0 && l < 4) {
      float s = boutv;
#pragma unroll
      for (int ww = 0; ww < 4; ++ww) s += out_part[cur ^ 1][l][ww];
      out[(size_t)(wg * 4 + l) * T_LEN + (t - 1)] = s;
    }

    // prefetch x_{t+1} (rows 0..3; first 2 waves)
    float xval = 0.0f;
    if (tid < 128) {
      const int tn = (t + 1 < T_LEN) ? (t + 1) : (T_LEN - 1);
      xval = xp[(size_t)tn * 32];
    }

    // ---- h K-loop: ks0..5 all-reg; ks6..7 o from LDS ----
    f32x4 acc[4][4];
    {
      const bf16x8 a = *reinterpret_cast<const bf16x8*>(ArowC + akoff);
#pragma unroll
      for (int nt = 0; nt < 4; ++nt)
        acc[0][nt] = __builtin_amdgcn_mfma_f32_16x16x32_bf16(a, Bf[0][nt], z4, 0, 0, 0);
#pragma unroll
      for (int nt = 0; nt < 4; ++nt)
        acc[1][nt] = __builtin_amdgcn_mfma_f32_16x16x32_bf16(a, Bg[0][nt], z4, 0, 0, 0);
#pragma unroll
      for (int nt = 0; nt < 4; ++nt)
        acc[2][nt] = __builtin_amdgcn_mfma_f32_16x16x32_bf16(a, Bo[0][nt], z4, 0, 0, 0);
    }
#pragma unroll
    for (int ks = 1; ks < 8; ++ks) {
      const bf16x8 a = *reinterpret_cast<const bf16x8*>(ArowC + ks * 32 + akoff);
#pragma unroll
      for (int nt = 0; nt < 4; ++nt)
        acc[0][nt] = __builtin_amdgcn_mfma_f32_16x16x32_bf16(a, Bf[ks][nt], acc[0][nt], 0, 0, 0);
#pragma unroll
      for (int nt = 0; nt < 4; ++nt)
        acc[1][nt] = __builtin_amdgcn_mfma_f32_16x16x32_bf16(a, Bg[ks][nt], acc[1][nt], 0, 0, 0);
      if (ks < 6) {
#pragma unroll
        for (int nt = 0; nt < 4; ++nt)
          acc[2][nt] = __builtin_amdgcn_mfma_f32_16x16x32_bf16(a, Bo[ks][nt], acc[2][nt], 0, 0, 0);
      } else {
#pragma unroll
        for (int nt = 0; nt < 4; ++nt) {
          const bf16x8 b = *reinterpret_cast<const bf16x8*>(bo2 + ((ks - 6) * 4 + nt) * 512 + l * 8);
          acc[2][nt] = __builtin_amdgcn_mfma_f32_16x16x32_bf16(a, b, acc[2][nt], 0, 0, 0);
        }
      }
    }
    // ---- x K-step (B from LDS): f,g,o accumulate; i starts fresh ----
    {
      const bf16x8 ax = *reinterpret_cast<const bf16x8*>(ArowC + 256 + akoff);
#pragma unroll
      for (int g = 0; g < 3; ++g) {
#pragma unroll
        for (int nt = 0; nt < 4; ++nt) {
          const bf16x8 b = *reinterpret_cast<const bf16x8*>(bxw + (g * 4 + nt) * 512 + l * 8);
          acc[g][nt] = __builtin_amdgcn_mfma_f32_16x16x32_bf16(ax, b, acc[g][nt], 0, 0, 0);
        }
      }
#pragma unroll
      for (int nt = 0; nt < 4; ++nt) {
        const bf16x8 b = *reinterpret_cast<const bf16x8*>(bxw + (12 + nt) * 512 + l * 8);
        acc[3][nt] = __builtin_amdgcn_mfma_f32_16x16x32_bf16(ax, b, z4, 0, 0, 0);
      }
    }

    // ---- activations: 4 gate-sets/lane (row = lg, ch = w*64 + nt*16 + lr) ----
    float po = 0.0f;
#pragma unroll
    for (int nt = 0; nt < 4; ++nt) {
      const float fpre = acc[0][nt][0] + bias[0][nt];
      const float gpre = acc[1][nt][0] + bias[1][nt];
      const float opre = acc[2][nt][0] + bias[2][nt];
      const float ipre = acc[3][nt][0] + bias[3][nt];
      const float sf = sigm(fpre);
      const float tg = tanh_(gpre);
      const float so = sigm(opre);
      const float si = sigm(ipre);
      const float c  = sf * cst[nt] + si * tg;
      cst[nt] = c;
      const float hv = so * tanh_(c);
      Anxt[(4 * lg) * ASTR + (w * 64 + nt * 16 + lr)] = f2bf(hv);
      po += so * woutv[nt];
    }

    // x_{t+1} into ALTERNATE buffer
    if (tid < 128) Anxt[(4 * (tid >> 5)) * ASTR + 256 + (tid & 31)] = f2bf(xval);

    // po reduce over the 16 lr-lanes -> (row = lg, wave w)
#pragma unroll
    for (int mk = 1; mk < 16; mk <<= 1) {
      po += __shfl_xor(po, mk, 64);
    }
    if (lr == 0) out_part[cur][lg][w] = po;

    __syncthreads();  // single per-step barrier
  }

  // final output
  if (w == 0 && l < 4) {
    float s = boutv;
#pragma unroll
    for (int ww = 0; ww < 4; ++ww) s += out_part[(T_LEN - 1) & 1][l][ww];
    out[(size_t)(wg * 4 + l) * T_LEN + (T_LEN - 1)] = s;
  }
}

extern "C" void kernel_launch(void* const* d_in, const int* in_sizes, int n_in,
                              void* d_out, int out_size, void* d_ws, size_t ws_size,
                              hipStream_t stream) {
  const float* x    = (const float*)d_in[0];
  const float* c0   = (const float*)d_in[1];
  const float* h0   = (const float*)d_in[2];
  const float* Wi   = (const float*)d_in[3];
  const float* bi   = (const float*)d_in[4];
  const float* Wfx  = (const float*)d_in[5];
  const float* bfx  = (const float*)d_in[6];
  const float* Wfh  = (const float*)d_in[7];
  const float* bfh  = (const float*)d_in[8];
  const float* Wgx  = (const float*)d_in[9];
  const float* bgx  = (const float*)d_in[10];
  const float* Wgh  = (const float*)d_in[11];
  const float* bgh  = (const float*)d_in[12];
  const float* Wox  = (const float*)d_in[13];
  const float* box_ = (const float*)d_in[14];
  const float* Woh  = (const float*)d_in[15];
  const float* boh  = (const float*)d_in[16];
  const float* Wout = (const float*)d_in[17];
  const float* bout = (const float*)d_in[18];

  ealstm_fused<<<dim3(32), dim3(256), 0, stream>>>(
      x, c0, h0, Wi, bi, Wfx, bfx, Wfh, bfh,
      Wgx, bgx, Wgh, bgh, Wox, box_, Woh, boh, Wout, bout,
      (float*)d_out);
}

// Round 12
// 3066.308 us; speedup vs baseline: 1.5009x; 1.5009x over previous
//
#include <hip/hip_runtime.h>
#include <hip/hip_bf16.h>

// EA-LSTM persistent kernel for MI355X (gfx950), round 12.
// B=128, T=2048, DYN=8, STAT=24, H=256, OUT=1.
// R6 skeleton (proven 4060us): 32 WGs x 512 thr (8 waves, 2/SIMD -> TLP),
// batch row b staged at A-row 4b so MFMA D r==0 gives one gate-set per
// (lane,nt); wave w owns ch [w*32,(w+1)*32); one barrier/step.
// CHANGE vs R6: weight placement flipped. Registers now hold f,g ks0..7 AND
// o ks0..6 (184 regs); LDS holds only o-ks7 + the x-projection frags
// (read once per step). LDS reads: 25 -> 19 b128/wave/step (152/CU ~1820cyc,
// below the 2170cyc MFMA issue floor). Bias folded into epilogue (z4 C-init).

#define T_LEN 2048
#define HD 256

typedef __attribute__((ext_vector_type(8))) short bf16x8;
typedef __attribute__((ext_vector_type(4))) float f32x4;

#define LOG2E 1.4426950408889634f

__device__ __forceinline__ short f2bf(float f) {
  unsigned u = __float_as_uint(f);
  unsigned r = (u + 0x7fffu + ((u >> 16) & 1u)) >> 16;
  return (short)r;
}

__device__ __forceinline__ bf16x8 loadw8(const float* p) {
  bf16x8 r;
#pragma unroll
  for (int i = 0; i < 8; ++i) r[i] = f2bf(p[i]);
  return r;
}

__device__ __forceinline__ float sigm(float x) {
  float e = __builtin_amdgcn_exp2f(-LOG2E * x);
  return __builtin_amdgcn_rcpf(1.0f + e);
}

// clamp-free tanh: 1 - 2/(e^{2x}+1); saturates to +/-1, NaN-free.
__device__ __forceinline__ float tanh_(float x) {
  float e = __builtin_amdgcn_exp2f((2.0f * LOG2E) * x);
  return 1.0f - 2.0f * __builtin_amdgcn_rcpf(e + 1.0f);
}

// A tile: 16 rows x 296 cols bf16 (0..255 = h, 256..287 = x_t, 288+ pad).
// Valid batch rows at A-rows {0,4,8,12}; other rows stay zero.
#define ASTR 296
#define ABUF (16 * ASTR)

__global__ __launch_bounds__(512, 2) void ealstm_kernel(
    const float* __restrict__ x, const float* __restrict__ c0, const float* __restrict__ h0,
    const float* __restrict__ Wi, const float* __restrict__ bi,
    const float* __restrict__ Wfx, const float* __restrict__ bfx,
    const float* __restrict__ Wfh, const float* __restrict__ bfh,
    const float* __restrict__ Wgx, const float* __restrict__ bgx,
    const float* __restrict__ Wgh, const float* __restrict__ bgh,
    const float* __restrict__ Wox, const float* __restrict__ box_,
    const float* __restrict__ Woh, const float* __restrict__ boh,
    const float* __restrict__ Wout, const float* __restrict__ bout,
    float* __restrict__ out)
{
  __shared__ __attribute__((aligned(16))) short A_sh[2 * ABUF];       // 18944 B
  __shared__ __attribute__((aligned(16))) short Bx_sh[8 * 8 * 512];   // 65536 B
  __shared__ __attribute__((aligned(16))) short Bo7_sh[8 * 2 * 512];  // 16384 B
  __shared__ float out_part[2][4][8];                                 // 256 B

  const int tid = threadIdx.x;
  const int w   = tid >> 6;   // wave 0..7, owns ch [w*32, w*32+32)
  const int l   = tid & 63;
  const int lr  = l & 15;
  const int lg  = l >> 4;     // activation row = lg (A-row trick)
  const int n0  = w * 32;
  const int wg  = blockIdx.x; // 4-row batch block

  // ---- register-resident weights: f,g ks0..7; o ks0..6 ----
  bf16x8 Bf[8][2], Bg[8][2], Bo[7][2];
#pragma unroll
  for (int ks = 0; ks < 8; ++ks) {
#pragma unroll
    for (int nt = 0; nt < 2; ++nt) {
      const int n = n0 + nt * 16 + lr;
      const int k = ks * 32 + lg * 8;
      Bf[ks][nt] = loadw8(Wfh + n * HD + k);
      Bg[ks][nt] = loadw8(Wgh + n * HD + k);
      if (ks < 7) Bo[ks][nt] = loadw8(Woh + n * HD + k);
    }
  }

  // ---- LDS-resident: o ks7 + x-projection frags ----
  short* bo7 = Bo7_sh + w * 1024;
#pragma unroll
  for (int nt = 0; nt < 2; ++nt) {
    const int n = n0 + nt * 16 + lr;
    bf16x8 fr = loadw8(Woh + n * HD + 7 * 32 + lg * 8);
    *reinterpret_cast<bf16x8*>(bo7 + nt * 512 + l * 8) = fr;
  }
  short* bxw = Bx_sh + w * 4096;
  {
    bf16x8 z = (bf16x8)(short)0;
    const float* WxArr[3] = {Wfx, Wgx, Wox};
#pragma unroll
    for (int nt = 0; nt < 2; ++nt) {
      const int n = n0 + nt * 16 + lr;
#pragma unroll
      for (int g = 0; g < 3; ++g) {
        bf16x8 fr = (lg == 0) ? loadw8(WxArr[g] + n * 8) : z;
        *reinterpret_cast<bf16x8*>(bxw + (g * 2 + nt) * 512 + l * 8) = fr;
      }
      bf16x8 fi = (lg >= 1) ? loadw8(Wi + n * 24 + (lg - 1) * 8) : z;
      *reinterpret_cast<bf16x8*>(bxw + (6 + nt) * 512 + l * 8) = fi;
    }
  }

  // ---- biases, Wout, c-state ----
  float bias[4][2], woutv[2], cst[2];
#pragma unroll
  for (int nt = 0; nt < 2; ++nt) {
    const int n = n0 + nt * 16 + lr;
    bias[0][nt] = bfx[n] + bfh[n];
    bias[1][nt] = bgx[n] + bgh[n];
    bias[2][nt] = box_[n] + boh[n];
    bias[3][nt] = bi[n];
    woutv[nt] = Wout[n];
    cst[nt] = c0[n];
  }
  const float boutv = bout[0];

  // ---- zero both A buffers; stage h0 at A-rows {0,4,8,12} and x_0 ----
  for (int idx = tid; idx < 2 * ABUF; idx += 512) A_sh[idx] = 0;
  __syncthreads();
  for (int idx = tid; idx < 4 * 256; idx += 512) {
    A_sh[(4 * (idx >> 8)) * ASTR + (idx & 255)] = f2bf(h0[idx & 255]);
  }
  if (tid < 128) {
    const int row = tid >> 5, k = tid & 31;
    A_sh[(4 * row) * ASTR + 256 + k] = f2bf(x[((size_t)(wg * 4 + row) * T_LEN) * 32 + k]);
  }
  __syncthreads();

  const float* xp = x + (size_t)(wg * 4 + ((tid >> 5) & 3)) * T_LEN * 32 + (tid & 31);
  const int akoff = lg * 8;
  const f32x4 z4 = {0.f, 0.f, 0.f, 0.f};

  for (int t = 0; t < T_LEN; ++t) {
    const int cur = t & 1;
    const short* ArowC = A_sh + cur * ABUF + lr * ASTR;
    short* Anxt = A_sh + (cur ^ 1) * ABUF;

    // finalize previous step's output (hidden under this step's MFMA phase)
    if (t > 0 && w == 0 && l < 4) {
      float s = boutv;
#pragma unroll
      for (int ww = 0; ww < 8; ++ww) s += out_part[cur ^ 1][l][ww];
      out[(size_t)(wg * 4 + l) * T_LEN + (t - 1)] = s;
    }

    // prefetch x_{t+1} (rows 0..3; first 4 half-waves)
    float xval = 0.0f;
    if (tid < 128) {
      const int tn = (t + 1 < T_LEN) ? (t + 1) : (T_LEN - 1);
      xval = xp[(size_t)tn * 32];
    }

    // ---- h K-loop (z4-C first step folds acc init) ----
    f32x4 acc[4][2];
    {
      const bf16x8 a = *reinterpret_cast<const bf16x8*>(ArowC + akoff);
      acc[0][0] = __builtin_amdgcn_mfma_f32_16x16x32_bf16(a, Bf[0][0], z4, 0, 0, 0);
      acc[0][1] = __builtin_amdgcn_mfma_f32_16x16x32_bf16(a, Bf[0][1], z4, 0, 0, 0);
      acc[1][0] = __builtin_amdgcn_mfma_f32_16x16x32_bf16(a, Bg[0][0], z4, 0, 0, 0);
      acc[1][1] = __builtin_amdgcn_mfma_f32_16x16x32_bf16(a, Bg[0][1], z4, 0, 0, 0);
      acc[2][0] = __builtin_amdgcn_mfma_f32_16x16x32_bf16(a, Bo[0][0], z4, 0, 0, 0);
      acc[2][1] = __builtin_amdgcn_mfma_f32_16x16x32_bf16(a, Bo[0][1], z4, 0, 0, 0);
    }
#pragma unroll
    for (int ks = 1; ks < 8; ++ks) {
      const bf16x8 a = *reinterpret_cast<const bf16x8*>(ArowC + ks * 32 + akoff);
      acc[0][0] = __builtin_amdgcn_mfma_f32_16x16x32_bf16(a, Bf[ks][0], acc[0][0], 0, 0, 0);
      acc[0][1] = __builtin_amdgcn_mfma_f32_16x16x32_bf16(a, Bf[ks][1], acc[0][1], 0, 0, 0);
      acc[1][0] = __builtin_amdgcn_mfma_f32_16x16x32_bf16(a, Bg[ks][0], acc[1][0], 0, 0, 0);
      acc[1][1] = __builtin_amdgcn_mfma_f32_16x16x32_bf16(a, Bg[ks][1], acc[1][1], 0, 0, 0);
      if (ks < 7) {
        acc[2][0] = __builtin_amdgcn_mfma_f32_16x16x32_bf16(a, Bo[ks][0], acc[2][0], 0, 0, 0);
        acc[2][1] = __builtin_amdgcn_mfma_f32_16x16x32_bf16(a, Bo[ks][1], acc[2][1], 0, 0, 0);
      } else {
        const bf16x8 b0 = *reinterpret_cast<const bf16x8*>(bo7 + 0 * 512 + l * 8);
        const bf16x8 b1 = *reinterpret_cast<const bf16x8*>(bo7 + 1 * 512 + l * 8);
        acc[2][0] = __builtin_amdgcn_mfma_f32_16x16x32_bf16(a, b0, acc[2][0], 0, 0, 0);
        acc[2][1] = __builtin_amdgcn_mfma_f32_16x16x32_bf16(a, b1, acc[2][1], 0, 0, 0);
      }
    }
    // ---- x K-step (B from LDS): f,g,o accumulate; i starts fresh ----
    {
      const bf16x8 ax = *reinterpret_cast<const bf16x8*>(ArowC + 256 + akoff);
#pragma unroll
      for (int g = 0; g < 3; ++g) {
#pragma unroll
        for (int nt = 0; nt < 2; ++nt) {
          const bf16x8 b = *reinterpret_cast<const bf16x8*>(bxw + (g * 2 + nt) * 512 + l * 8);
          acc[g][nt] = __builtin_amdgcn_mfma_f32_16x16x32_bf16(ax, b, acc[g][nt], 0, 0, 0);
        }
      }
#pragma unroll
      for (int nt = 0; nt < 2; ++nt) {
        const bf16x8 b = *reinterpret_cast<const bf16x8*>(bxw + (6 + nt) * 512 + l * 8);
        acc[3][nt] = __builtin_amdgcn_mfma_f32_16x16x32_bf16(ax, b, z4, 0, 0, 0);
      }
    }

    // ---- activations: 2 gate-sets per lane (row = lg, ch = n0 + nt*16 + lr) ----
    float po = 0.0f;
    short hpk[2];
#pragma unroll
    for (int nt = 0; nt < 2; ++nt) {
      const float fpre = acc[0][nt][0] + bias[0][nt];
      const float gpre = acc[1][nt][0] + bias[1][nt];
      const float opre = acc[2][nt][0] + bias[2][nt];
      const float ipre = acc[3][nt][0] + bias[3][nt];
      const float sf = sigm(fpre);
      const float tg = tanh_(gpre);
      const float so = sigm(opre);
      const float si = sigm(ipre);
      const float c  = sf * cst[nt] + si * tg;
      cst[nt] = c;
      const float hv = so * tanh_(c);
      hpk[nt] = f2bf(hv);
      po += so * woutv[nt];
    }

    // h-writes into ALTERNATE buffer at A-row 4*lg
    Anxt[(4 * lg) * ASTR + (n0 + lr)]      = hpk[0];
    Anxt[(4 * lg) * ASTR + (n0 + 16 + lr)] = hpk[1];
    // x_{t+1} into ALTERNATE buffer
    if (tid < 128) Anxt[(4 * (tid >> 5)) * ASTR + 256 + (tid & 31)] = f2bf(xval);

    // po reduce over the 16 lr-lanes -> (row = lg, wave w)
#pragma unroll
    for (int mk = 1; mk < 16; mk <<= 1) {
      po += __shfl_xor(po, mk, 64);
    }
    if (lr == 0) out_part[cur][lg][w] = po;

    __syncthreads();  // single per-step barrier
  }

  // final output
  if (w == 0 && l < 4) {
    float s = boutv;
#pragma unroll
    for (int ww = 0; ww < 8; ++ww) s += out_part[(T_LEN - 1) & 1][l][ww];
    out[(size_t)(wg * 4 + l) * T_LEN + (T_LEN - 1)] = s;
  }
}

extern "C" void kernel_launch(void* const* d_in, const int* in_sizes, int n_in,
                              void* d_out, int out_size, void* d_ws, size_t ws_size,
                              hipStream_t stream) {
  const float* x    = (const float*)d_in[0];
  const float* c0   = (const float*)d_in[1];
  const float* h0   = (const float*)d_in[2];
  const float* Wi   = (const float*)d_in[3];
  const float* bi   = (const float*)d_in[4];
  const float* Wfx  = (const float*)d_in[5];
  const float* bfx  = (const float*)d_in[6];
  const float* Wfh  = (const float*)d_in[7];
  const float* bfh  = (const float*)d_in[8];
  const float* Wgx  = (const float*)d_in[9];
  const float* bgx  = (const float*)d_in[10];
  const float* Wgh  = (const float*)d_in[11];
  const float* bgh  = (const float*)d_in[12];
  const float* Wox  = (const float*)d_in[13];
  const float* box_ = (const float*)d_in[14];
  const float* Woh  = (const float*)d_in[15];
  const float* boh  = (const float*)d_in[16];
  const float* Wout = (const float*)d_in[17];
  const float* bout = (const float*)d_in[18];

  ealstm_kernel<<<dim3(32), dim3(512), 0, stream>>>(
      x, c0, h0, Wi, bi, Wfx, bfx, Wfh, bfh,
      Wgx, bgx, Wgh, bgh, Wox, box_, Woh, boh, Wout, bout,
      (float*)d_out);
}

// Round 13
// 2997.289 us; speedup vs baseline: 1.5355x; 1.0230x over previous
//
#include <hip/hip_runtime.h>
#include <hip/hip_bf16.h>

// EA-LSTM persistent kernel for MI355X (gfx950), round 13.
// B=128, T=2048, DYN=8, STAT=24, H=256, OUT=1.
// R12 body (proven 3066us): 32 WGs x 512 thr (8 waves, 2/SIMD), batch row b
// staged at A-row 4b (MFMA D r==0 -> 1 gate-set per lane,nt), wave w owns
// ch [w*32,w*32+32); regs hold f,g ks0..7 + o ks0..6; LDS holds o-ks7 + x-frags.
// CHANGES vs R12:
//  1. Loop barrier = raw s_barrier + s_waitcnt lgkmcnt(0) ONLY (no vmcnt(0)
//     drain -> wave0's out[] store-ack and stray vmem no longer gate the step).
//     sched_barrier(0) after the asm per methodology rule #18.
//  2. po shuffle-reduce truncated 4 -> 2 steps; 4 partials per (row,wave)
//     stored; the extra adds run in wave0's shadowed finalizer.

#define T_LEN 2048
#define HD 256

typedef __attribute__((ext_vector_type(8))) short bf16x8;
typedef __attribute__((ext_vector_type(4))) float f32x4;

#define LOG2E 1.4426950408889634f

__device__ __forceinline__ short f2bf(float f) {
  unsigned u = __float_as_uint(f);
  unsigned r = (u + 0x7fffu + ((u >> 16) & 1u)) >> 16;
  return (short)r;
}

__device__ __forceinline__ bf16x8 loadw8(const float* p) {
  bf16x8 r;
#pragma unroll
  for (int i = 0; i < 8; ++i) r[i] = f2bf(p[i]);
  return r;
}

__device__ __forceinline__ float sigm(float x) {
  float e = __builtin_amdgcn_exp2f(-LOG2E * x);
  return __builtin_amdgcn_rcpf(1.0f + e);
}

// clamp-free tanh: 1 - 2/(e^{2x}+1); saturates to +/-1, NaN-free.
__device__ __forceinline__ float tanh_(float x) {
  float e = __builtin_amdgcn_exp2f((2.0f * LOG2E) * x);
  return 1.0f - 2.0f * __builtin_amdgcn_rcpf(e + 1.0f);
}

// Workgroup barrier that drains ONLY LDS ops (not vmem). The x-prefetch value
// is consumed by a ds_write before this point, whose data dependency already
// forces the needed vmcnt wait; out[] global stores need no drain.
__device__ __forceinline__ void wg_barrier_lgkm() {
  asm volatile("s_waitcnt lgkmcnt(0)" ::: "memory");
  __builtin_amdgcn_s_barrier();
  __builtin_amdgcn_sched_barrier(0);
}

// A tile: 16 rows x 296 cols bf16 (0..255 = h, 256..287 = x_t, 288+ pad).
// Valid batch rows at A-rows {0,4,8,12}; other rows stay zero.
#define ASTR 296
#define ABUF (16 * ASTR)

__global__ __launch_bounds__(512, 2) void ealstm_kernel(
    const float* __restrict__ x, const float* __restrict__ c0, const float* __restrict__ h0,
    const float* __restrict__ Wi, const float* __restrict__ bi,
    const float* __restrict__ Wfx, const float* __restrict__ bfx,
    const float* __restrict__ Wfh, const float* __restrict__ bfh,
    const float* __restrict__ Wgx, const float* __restrict__ bgx,
    const float* __restrict__ Wgh, const float* __restrict__ bgh,
    const float* __restrict__ Wox, const float* __restrict__ box_,
    const float* __restrict__ Woh, const float* __restrict__ boh,
    const float* __restrict__ Wout, const float* __restrict__ bout,
    float* __restrict__ out)
{
  __shared__ __attribute__((aligned(16))) short A_sh[2 * ABUF];       // 18944 B
  __shared__ __attribute__((aligned(16))) short Bx_sh[8 * 8 * 512];   // 65536 B
  __shared__ __attribute__((aligned(16))) short Bo7_sh[8 * 2 * 512];  // 16384 B
  __shared__ float out_part[2][4][32];                                // 1024 B

  const int tid = threadIdx.x;
  const int w   = tid >> 6;   // wave 0..7, owns ch [w*32, w*32+32)
  const int l   = tid & 63;
  const int lr  = l & 15;
  const int lg  = l >> 4;     // activation row = lg (A-row trick)
  const int n0  = w * 32;
  const int wg  = blockIdx.x; // 4-row batch block

  // ---- register-resident weights: f,g ks0..7; o ks0..6 ----
  bf16x8 Bf[8][2], Bg[8][2], Bo[7][2];
#pragma unroll
  for (int ks = 0; ks < 8; ++ks) {
#pragma unroll
    for (int nt = 0; nt < 2; ++nt) {
      const int n = n0 + nt * 16 + lr;
      const int k = ks * 32 + lg * 8;
      Bf[ks][nt] = loadw8(Wfh + n * HD + k);
      Bg[ks][nt] = loadw8(Wgh + n * HD + k);
      if (ks < 7) Bo[ks][nt] = loadw8(Woh + n * HD + k);
    }
  }

  // ---- LDS-resident: o ks7 + x-projection frags ----
  short* bo7 = Bo7_sh + w * 1024;
#pragma unroll
  for (int nt = 0; nt < 2; ++nt) {
    const int n = n0 + nt * 16 + lr;
    bf16x8 fr = loadw8(Woh + n * HD + 7 * 32 + lg * 8);
    *reinterpret_cast<bf16x8*>(bo7 + nt * 512 + l * 8) = fr;
  }
  short* bxw = Bx_sh + w * 4096;
  {
    bf16x8 z = (bf16x8)(short)0;
    const float* WxArr[3] = {Wfx, Wgx, Wox};
#pragma unroll
    for (int nt = 0; nt < 2; ++nt) {
      const int n = n0 + nt * 16 + lr;
#pragma unroll
      for (int g = 0; g < 3; ++g) {
        bf16x8 fr = (lg == 0) ? loadw8(WxArr[g] + n * 8) : z;
        *reinterpret_cast<bf16x8*>(bxw + (g * 2 + nt) * 512 + l * 8) = fr;
      }
      bf16x8 fi = (lg >= 1) ? loadw8(Wi + n * 24 + (lg - 1) * 8) : z;
      *reinterpret_cast<bf16x8*>(bxw + (6 + nt) * 512 + l * 8) = fi;
    }
  }

  // ---- biases, Wout, c-state ----
  float bias[4][2], woutv[2], cst[2];
#pragma unroll
  for (int nt = 0; nt < 2; ++nt) {
    const int n = n0 + nt * 16 + lr;
    bias[0][nt] = bfx[n] + bfh[n];
    bias[1][nt] = bgx[n] + bgh[n];
    bias[2][nt] = box_[n] + boh[n];
    bias[3][nt] = bi[n];
    woutv[nt] = Wout[n];
    cst[nt] = c0[n];
  }
  const float boutv = bout[0];

  // ---- zero both A buffers; stage h0 at A-rows {0,4,8,12} and x_0 ----
  for (int idx = tid; idx < 2 * ABUF; idx += 512) A_sh[idx] = 0;
  __syncthreads();
  for (int idx = tid; idx < 4 * 256; idx += 512) {
    A_sh[(4 * (idx >> 8)) * ASTR + (idx & 255)] = f2bf(h0[idx & 255]);
  }
  if (tid < 128) {
    const int row = tid >> 5, k = tid & 31;
    A_sh[(4 * row) * ASTR + 256 + k] = f2bf(x[((size_t)(wg * 4 + row) * T_LEN) * 32 + k]);
  }
  __syncthreads();

  const float* xp = x + (size_t)(wg * 4 + ((tid >> 5) & 3)) * T_LEN * 32 + (tid & 31);
  const int akoff = lg * 8;
  const f32x4 z4 = {0.f, 0.f, 0.f, 0.f};

  for (int t = 0; t < T_LEN; ++t) {
    const int cur = t & 1;
    const short* ArowC = A_sh + cur * ABUF + lr * ASTR;
    short* Anxt = A_sh + (cur ^ 1) * ABUF;

    // finalize previous step's output (hidden under this step's MFMA phase)
    if (t > 0 && w == 0 && l < 4) {
      float s = boutv;
#pragma unroll
      for (int ww = 0; ww < 32; ++ww) s += out_part[cur ^ 1][l][ww];
      out[(size_t)(wg * 4 + l) * T_LEN + (t - 1)] = s;
    }

    // prefetch x_{t+1} (rows 0..3)
    float xval = 0.0f;
    if (tid < 128) {
      const int tn = (t + 1 < T_LEN) ? (t + 1) : (T_LEN - 1);
      xval = xp[(size_t)tn * 32];
    }

    // ---- h K-loop (z4-C first step folds acc init) ----
    f32x4 acc[4][2];
    {
      const bf16x8 a = *reinterpret_cast<const bf16x8*>(ArowC + akoff);
      acc[0][0] = __builtin_amdgcn_mfma_f32_16x16x32_bf16(a, Bf[0][0], z4, 0, 0, 0);
      acc[0][1] = __builtin_amdgcn_mfma_f32_16x16x32_bf16(a, Bf[0][1], z4, 0, 0, 0);
      acc[1][0] = __builtin_amdgcn_mfma_f32_16x16x32_bf16(a, Bg[0][0], z4, 0, 0, 0);
      acc[1][1] = __builtin_amdgcn_mfma_f32_16x16x32_bf16(a, Bg[0][1], z4, 0, 0, 0);
      acc[2][0] = __builtin_amdgcn_mfma_f32_16x16x32_bf16(a, Bo[0][0], z4, 0, 0, 0);
      acc[2][1] = __builtin_amdgcn_mfma_f32_16x16x32_bf16(a, Bo[0][1], z4, 0, 0, 0);
    }
#pragma unroll
    for (int ks = 1; ks < 8; ++ks) {
      const bf16x8 a = *reinterpret_cast<const bf16x8*>(ArowC + ks * 32 + akoff);
      acc[0][0] = __builtin_amdgcn_mfma_f32_16x16x32_bf16(a, Bf[ks][0], acc[0][0], 0, 0, 0);
      acc[0][1] = __builtin_amdgcn_mfma_f32_16x16x32_bf16(a, Bf[ks][1], acc[0][1], 0, 0, 0);
      acc[1][0] = __builtin_amdgcn_mfma_f32_16x16x32_bf16(a, Bg[ks][0], acc[1][0], 0, 0, 0);
      acc[1][1] = __builtin_amdgcn_mfma_f32_16x16x32_bf16(a, Bg[ks][1], acc[1][1], 0, 0, 0);
      if (ks < 7) {
        acc[2][0] = __builtin_amdgcn_mfma_f32_16x16x32_bf16(a, Bo[ks][0], acc[2][0], 0, 0, 0);
        acc[2][1] = __builtin_amdgcn_mfma_f32_16x16x32_bf16(a, Bo[ks][1], acc[2][1], 0, 0, 0);
      } else {
        const bf16x8 b0 = *reinterpret_cast<const bf16x8*>(bo7 + 0 * 512 + l * 8);
        const bf16x8 b1 = *reinterpret_cast<const bf16x8*>(bo7 + 1 * 512 + l * 8);
        acc[2][0] = __builtin_amdgcn_mfma_f32_16x16x32_bf16(a, b0, acc[2][0], 0, 0, 0);
        acc[2][1] = __builtin_amdgcn_mfma_f32_16x16x32_bf16(a, b1, acc[2][1], 0, 0, 0);
      }
    }
    // ---- x K-step (B from LDS): f,g,o accumulate; i starts fresh ----
    {
      const bf16x8 ax = *reinterpret_cast<const bf16x8*>(ArowC + 256 + akoff);
#pragma unroll
      for (int g = 0; g < 3; ++g) {
#pragma unroll
        for (int nt = 0; nt < 2; ++nt) {
          const bf16x8 b = *reinterpret_cast<const bf16x8*>(bxw + (g * 2 + nt) * 512 + l * 8);
          acc[g][nt] = __builtin_amdgcn_mfma_f32_16x16x32_bf16(ax, b, acc[g][nt], 0, 0, 0);
        }
      }
#pragma unroll
      for (int nt = 0; nt < 2; ++nt) {
        const bf16x8 b = *reinterpret_cast<const bf16x8*>(bxw + (6 + nt) * 512 + l * 8);
        acc[3][nt] = __builtin_amdgcn_mfma_f32_16x16x32_bf16(ax, b, z4, 0, 0, 0);
      }
    }

    // ---- activations: 2 gate-sets per lane (row = lg, ch = n0 + nt*16 + lr) ----
    float po = 0.0f;
    short hpk[2];
#pragma unroll
    for (int nt = 0; nt < 2; ++nt) {
      const float fpre = acc[0][nt][0] + bias[0][nt];
      const float gpre = acc[1][nt][0] + bias[1][nt];
      const float opre = acc[2][nt][0] + bias[2][nt];
      const float ipre = acc[3][nt][0] + bias[3][nt];
      const float sf = sigm(fpre);
      const float tg = tanh_(gpre);
      const float so = sigm(opre);
      const float si = sigm(ipre);
      const float c  = sf * cst[nt] + si * tg;
      cst[nt] = c;
      const float hv = so * tanh_(c);
      hpk[nt] = f2bf(hv);
      po += so * woutv[nt];
    }

    // h-writes into ALTERNATE buffer at A-row 4*lg
    Anxt[(4 * lg) * ASTR + (n0 + lr)]      = hpk[0];
    Anxt[(4 * lg) * ASTR + (n0 + 16 + lr)] = hpk[1];
    // x_{t+1} into ALTERNATE buffer
    if (tid < 128) Anxt[(4 * (tid >> 5)) * ASTR + 256 + (tid & 31)] = f2bf(xval);

    // po partial-reduce: only 2 shuffle steps; 4 partials per (row, wave)
    po += __shfl_xor(po, 1, 64);
    po += __shfl_xor(po, 2, 64);
    if ((lr & 3) == 0) out_part[cur][lg][w * 4 + (lr >> 2)] = po;

    wg_barrier_lgkm();  // single per-step barrier, LDS-drain only
  }

  // final output
  if (w == 0 && l < 4) {
    float s = boutv;
#pragma unroll
    for (int ww = 0; ww < 32; ++ww) s += out_part[(T_LEN - 1) & 1][l][ww];
    out[(size_t)(wg * 4 + l) * T_LEN + (T_LEN - 1)] = s;
  }
}

extern "C" void kernel_launch(void* const* d_in, const int* in_sizes, int n_in,
                              void* d_out, int out_size, void* d_ws, size_t ws_size,
                              hipStream_t stream) {
  const float* x    = (const float*)d_in[0];
  const float* c0   = (const float*)d_in[1];
  const float* h0   = (const float*)d_in[2];
  const float* Wi   = (const float*)d_in[3];
  const float* bi   = (const float*)d_in[4];
  const float* Wfx  = (const float*)d_in[5];
  const float* bfx  = (const float*)d_in[6];
  const float* Wfh  = (const float*)d_in[7];
  const float* bfh  = (const float*)d_in[8];
  const float* Wgx  = (const float*)d_in[9];
  const float* bgx  = (const float*)d_in[10];
  const float* Wgh  = (const float*)d_in[11];
  const float* bgh  = (const float*)d_in[12];
  const float* Wox  = (const float*)d_in[13];
  const float* box_ = (const float*)d_in[14];
  const float* Woh  = (const float*)d_in[15];
  const float* boh  = (const float*)d_in[16];
  const float* Wout = (const float*)d_in[17];
  const float* bout = (const float*)d_in[18];

  ealstm_kernel<<<dim3(32), dim3(512), 0, stream>>>(
      x, c0, h0, Wi, bi, Wfx, bfx, Wfh, bfh,
      Wgx, bgx, Wgh, bgh, Wox, box_, Woh, boh, Wout, bout,
      (float*)d_out);
}

// Round 14
// 2805.910 us; speedup vs baseline: 1.6402x; 1.0682x over previous
//
#include <hip/hip_runtime.h>
#include <hip/hip_bf16.h>

// EA-LSTM persistent kernel for MI355X (gfx950), round 14.
// B=128, T=2048, DYN=8, STAT=24, H=256, OUT=1.
// R13 body (proven 2997us): 32 WGs x 512 thr (8 waves, 2/SIMD), batch row b
// staged at A-row 4b (MFMA D r==0 -> 1 gate-set per lane,nt), wave w owns
// ch [w*32,w*32+32); regs hold f,g ks0..7 + o ks0..6; LDS holds o-ks7 + x-frags;
// lgkm-only barrier; po 2-step shuffle reduce.
// CHANGES vs R13:
//  1. x staging moved from waves 0,1 (tid<128) to waves 6,7 (tid>=384) --
//     wave 0 already carries the out finalize+store; spread the stragglers.
//  2. s_setprio(1) around the MFMA cluster (waves drift within a step: one
//     wave in activations while the other MFMAs -> role diversity, T5 regime).
//  3. i-gate bias folded into the i x-MFMA C-operand (shorter epilogue chain).
//  4. First 4 A-frag reads grouped before the first MFMA (batch lgkmcnt).

#define T_LEN 2048
#define HD 256

typedef __attribute__((ext_vector_type(8))) short bf16x8;
typedef __attribute__((ext_vector_type(4))) float f32x4;

#define LOG2E 1.4426950408889634f

__device__ __forceinline__ short f2bf(float f) {
  unsigned u = __float_as_uint(f);
  unsigned r = (u + 0x7fffu + ((u >> 16) & 1u)) >> 16;
  return (short)r;
}

__device__ __forceinline__ bf16x8 loadw8(const float* p) {
  bf16x8 r;
#pragma unroll
  for (int i = 0; i < 8; ++i) r[i] = f2bf(p[i]);
  return r;
}

__device__ __forceinline__ float sigm(float x) {
  float e = __builtin_amdgcn_exp2f(-LOG2E * x);
  return __builtin_amdgcn_rcpf(1.0f + e);
}

// clamp-free tanh: 1 - 2/(e^{2x}+1); saturates to +/-1, NaN-free.
__device__ __forceinline__ float tanh_(float x) {
  float e = __builtin_amdgcn_exp2f((2.0f * LOG2E) * x);
  return 1.0f - 2.0f * __builtin_amdgcn_rcpf(e + 1.0f);
}

// Workgroup barrier draining ONLY LDS ops (not vmem). The x-prefetch value is
// consumed by a ds_write before this point (data dep forces its vmcnt wait);
// out[] global stores need no drain.
__device__ __forceinline__ void wg_barrier_lgkm() {
  asm volatile("s_waitcnt lgkmcnt(0)" ::: "memory");
  __builtin_amdgcn_s_barrier();
  __builtin_amdgcn_sched_barrier(0);
}

// A tile: 16 rows x 296 cols bf16 (0..255 = h, 256..287 = x_t, 288+ pad).
// Valid batch rows at A-rows {0,4,8,12}; other rows stay zero.
#define ASTR 296
#define ABUF (16 * ASTR)

__global__ __launch_bounds__(512, 2) void ealstm_kernel(
    const float* __restrict__ x, const float* __restrict__ c0, const float* __restrict__ h0,
    const float* __restrict__ Wi, const float* __restrict__ bi,
    const float* __restrict__ Wfx, const float* __restrict__ bfx,
    const float* __restrict__ Wfh, const float* __restrict__ bfh,
    const float* __restrict__ Wgx, const float* __restrict__ bgx,
    const float* __restrict__ Wgh, const float* __restrict__ bgh,
    const float* __restrict__ Wox, const float* __restrict__ box_,
    const float* __restrict__ Woh, const float* __restrict__ boh,
    const float* __restrict__ Wout, const float* __restrict__ bout,
    float* __restrict__ out)
{
  __shared__ __attribute__((aligned(16))) short A_sh[2 * ABUF];       // 18944 B
  __shared__ __attribute__((aligned(16))) short Bx_sh[8 * 8 * 512];   // 65536 B
  __shared__ __attribute__((aligned(16))) short Bo7_sh[8 * 2 * 512];  // 16384 B
  __shared__ float out_part[2][4][32];                                // 1024 B

  const int tid = threadIdx.x;
  const int w   = tid >> 6;   // wave 0..7, owns ch [w*32, w*32+32)
  const int l   = tid & 63;
  const int lr  = l & 15;
  const int lg  = l >> 4;     // activation row = lg (A-row trick)
  const int n0  = w * 32;
  const int wg  = blockIdx.x; // 4-row batch block
  const bool xstage = (tid >= 384);  // waves 6,7 stage x (wave0 does finalize)

  // ---- register-resident weights: f,g ks0..7; o ks0..6 ----
  bf16x8 Bf[8][2], Bg[8][2], Bo[7][2];
#pragma unroll
  for (int ks = 0; ks < 8; ++ks) {
#pragma unroll
    for (int nt = 0; nt < 2; ++nt) {
      const int n = n0 + nt * 16 + lr;
      const int k = ks * 32 + lg * 8;
      Bf[ks][nt] = loadw8(Wfh + n * HD + k);
      Bg[ks][nt] = loadw8(Wgh + n * HD + k);
      if (ks < 7) Bo[ks][nt] = loadw8(Woh + n * HD + k);
    }
  }

  // ---- LDS-resident: o ks7 + x-projection frags ----
  short* bo7 = Bo7_sh + w * 1024;
#pragma unroll
  for (int nt = 0; nt < 2; ++nt) {
    const int n = n0 + nt * 16 + lr;
    bf16x8 fr = loadw8(Woh + n * HD + 7 * 32 + lg * 8);
    *reinterpret_cast<bf16x8*>(bo7 + nt * 512 + l * 8) = fr;
  }
  short* bxw = Bx_sh + w * 4096;
  {
    bf16x8 z = (bf16x8)(short)0;
    const float* WxArr[3] = {Wfx, Wgx, Wox};
#pragma unroll
    for (int nt = 0; nt < 2; ++nt) {
      const int n = n0 + nt * 16 + lr;
#pragma unroll
      for (int g = 0; g < 3; ++g) {
        bf16x8 fr = (lg == 0) ? loadw8(WxArr[g] + n * 8) : z;
        *reinterpret_cast<bf16x8*>(bxw + (g * 2 + nt) * 512 + l * 8) = fr;
      }
      bf16x8 fi = (lg >= 1) ? loadw8(Wi + n * 24 + (lg - 1) * 8) : z;
      *reinterpret_cast<bf16x8*>(bxw + (6 + nt) * 512 + l * 8) = fi;
    }
  }

  // ---- biases, Wout, c-state ----
  float bias[4][2], woutv[2], cst[2];
#pragma unroll
  for (int nt = 0; nt < 2; ++nt) {
    const int n = n0 + nt * 16 + lr;
    bias[0][nt] = bfx[n] + bfh[n];
    bias[1][nt] = bgx[n] + bgh[n];
    bias[2][nt] = box_[n] + boh[n];
    bias[3][nt] = bi[n];
    woutv[nt] = Wout[n];
    cst[nt] = c0[n];
  }
  const float boutv = bout[0];

  // ---- zero both A buffers; stage h0 at A-rows {0,4,8,12} and x_0 ----
  for (int idx = tid; idx < 2 * ABUF; idx += 512) A_sh[idx] = 0;
  __syncthreads();
  for (int idx = tid; idx < 4 * 256; idx += 512) {
    A_sh[(4 * (idx >> 8)) * ASTR + (idx & 255)] = f2bf(h0[idx & 255]);
  }
  if (xstage) {
    const int row = (tid >> 5) & 3, k = tid & 31;
    A_sh[(4 * row) * ASTR + 256 + k] = f2bf(x[((size_t)(wg * 4 + row) * T_LEN) * 32 + k]);
  }
  __syncthreads();

  const float* xp = x + (size_t)(wg * 4 + ((tid >> 5) & 3)) * T_LEN * 32 + (tid & 31);
  const int akoff = lg * 8;
  const f32x4 z4 = {0.f, 0.f, 0.f, 0.f};

  for (int t = 0; t < T_LEN; ++t) {
    const int cur = t & 1;
    const short* ArowC = A_sh + cur * ABUF + lr * ASTR;
    short* Anxt = A_sh + (cur ^ 1) * ABUF;

    // finalize previous step's output (hidden under this step's MFMA phase)
    if (t > 0 && w == 0 && l < 4) {
      float s = boutv;
#pragma unroll
      for (int ww = 0; ww < 32; ++ww) s += out_part[cur ^ 1][l][ww];
      out[(size_t)(wg * 4 + l) * T_LEN + (t - 1)] = s;
    }

    // prefetch x_{t+1} (rows 0..3; waves 6,7)
    float xval = 0.0f;
    if (xstage) {
      const int tn = (t + 1 < T_LEN) ? (t + 1) : (T_LEN - 1);
      xval = xp[(size_t)tn * 32];
    }

    // ---- h K-loop (z4-C first step folds acc init); setprio around MFMAs ----
    f32x4 acc[4][2];
    // group the first 4 A-frag reads so lgkmcnt waits batch
    const bf16x8 a0 = *reinterpret_cast<const bf16x8*>(ArowC + 0 * 32 + akoff);
    const bf16x8 a1 = *reinterpret_cast<const bf16x8*>(ArowC + 1 * 32 + akoff);
    const bf16x8 a2 = *reinterpret_cast<const bf16x8*>(ArowC + 2 * 32 + akoff);
    const bf16x8 a3 = *reinterpret_cast<const bf16x8*>(ArowC + 3 * 32 + akoff);
    __builtin_amdgcn_s_setprio(1);
    {
      acc[0][0] = __builtin_amdgcn_mfma_f32_16x16x32_bf16(a0, Bf[0][0], z4, 0, 0, 0);
      acc[0][1] = __builtin_amdgcn_mfma_f32_16x16x32_bf16(a0, Bf[0][1], z4, 0, 0, 0);
      acc[1][0] = __builtin_amdgcn_mfma_f32_16x16x32_bf16(a0, Bg[0][0], z4, 0, 0, 0);
      acc[1][1] = __builtin_amdgcn_mfma_f32_16x16x32_bf16(a0, Bg[0][1], z4, 0, 0, 0);
      acc[2][0] = __builtin_amdgcn_mfma_f32_16x16x32_bf16(a0, Bo[0][0], z4, 0, 0, 0);
      acc[2][1] = __builtin_amdgcn_mfma_f32_16x16x32_bf16(a0, Bo[0][1], z4, 0, 0, 0);
    }
    {
      const bf16x8 aa[3] = {a1, a2, a3};
#pragma unroll
      for (int ks = 1; ks < 4; ++ks) {
        const bf16x8 a = aa[ks - 1];
        acc[0][0] = __builtin_amdgcn_mfma_f32_16x16x32_bf16(a, Bf[ks][0], acc[0][0], 0, 0, 0);
        acc[0][1] = __builtin_amdgcn_mfma_f32_16x16x32_bf16(a, Bf[ks][1], acc[0][1], 0, 0, 0);
        acc[1][0] = __builtin_amdgcn_mfma_f32_16x16x32_bf16(a, Bg[ks][0], acc[1][0], 0, 0, 0);
        acc[1][1] = __builtin_amdgcn_mfma_f32_16x16x32_bf16(a, Bg[ks][1], acc[1][1], 0, 0, 0);
        acc[2][0] = __builtin_amdgcn_mfma_f32_16x16x32_bf16(a, Bo[ks][0], acc[2][0], 0, 0, 0);
        acc[2][1] = __builtin_amdgcn_mfma_f32_16x16x32_bf16(a, Bo[ks][1], acc[2][1], 0, 0, 0);
      }
    }
#pragma unroll
    for (int ks = 4; ks < 8; ++ks) {
      const bf16x8 a = *reinterpret_cast<const bf16x8*>(ArowC + ks * 32 + akoff);
      acc[0][0] = __builtin_amdgcn_mfma_f32_16x16x32_bf16(a, Bf[ks][0], acc[0][0], 0, 0, 0);
      acc[0][1] = __builtin_amdgcn_mfma_f32_16x16x32_bf16(a, Bf[ks][1], acc[0][1], 0, 0, 0);
      acc[1][0] = __builtin_amdgcn_mfma_f32_16x16x32_bf16(a, Bg[ks][0], acc[1][0], 0, 0, 0);
      acc[1][1] = __builtin_amdgcn_mfma_f32_16x16x32_bf16(a, Bg[ks][1], acc[1][1], 0, 0, 0);
      if (ks < 7) {
        acc[2][0] = __builtin_amdgcn_mfma_f32_16x16x32_bf16(a, Bo[ks][0], acc[2][0], 0, 0, 0);
        acc[2][1] = __builtin_amdgcn_mfma_f32_16x16x32_bf16(a, Bo[ks][1], acc[2][1], 0, 0, 0);
      } else {
        const bf16x8 b0 = *reinterpret_cast<const bf16x8*>(bo7 + 0 * 512 + l * 8);
        const bf16x8 b1 = *reinterpret_cast<const bf16x8*>(bo7 + 1 * 512 + l * 8);
        acc[2][0] = __builtin_amdgcn_mfma_f32_16x16x32_bf16(a, b0, acc[2][0], 0, 0, 0);
        acc[2][1] = __builtin_amdgcn_mfma_f32_16x16x32_bf16(a, b1, acc[2][1], 0, 0, 0);
      }
    }
    // ---- x K-step (B from LDS): f,g,o accumulate; i C-init = bias splat ----
    {
      const bf16x8 ax = *reinterpret_cast<const bf16x8*>(ArowC + 256 + akoff);
#pragma unroll
      for (int g = 0; g < 3; ++g) {
#pragma unroll
        for (int nt = 0; nt < 2; ++nt) {
          const bf16x8 b = *reinterpret_cast<const bf16x8*>(bxw + (g * 2 + nt) * 512 + l * 8);
          acc[g][nt] = __builtin_amdgcn_mfma_f32_16x16x32_bf16(ax, b, acc[g][nt], 0, 0, 0);
        }
      }
#pragma unroll
      for (int nt = 0; nt < 2; ++nt) {
        const bf16x8 b = *reinterpret_cast<const bf16x8*>(bxw + (6 + nt) * 512 + l * 8);
        f32x4 cb; cb[0] = bias[3][nt]; cb[1] = bias[3][nt]; cb[2] = bias[3][nt]; cb[3] = bias[3][nt];
        acc[3][nt] = __builtin_amdgcn_mfma_f32_16x16x32_bf16(ax, b, cb, 0, 0, 0);
      }
    }
    __builtin_amdgcn_s_setprio(0);

    // ---- activations: 2 gate-sets per lane (row = lg, ch = n0 + nt*16 + lr) ----
    float po = 0.0f;
    short hpk[2];
#pragma unroll
    for (int nt = 0; nt < 2; ++nt) {
      const float fpre = acc[0][nt][0] + bias[0][nt];
      const float gpre = acc[1][nt][0] + bias[1][nt];
      const float opre = acc[2][nt][0] + bias[2][nt];
      const float ipre = acc[3][nt][0];  // bias already in C
      const float sf = sigm(fpre);
      const float tg = tanh_(gpre);
      const float so = sigm(opre);
      const float si = sigm(ipre);
      const float c  = sf * cst[nt] + si * tg;
      cst[nt] = c;
      const float hv = so * tanh_(c);
      hpk[nt] = f2bf(hv);
      po += so * woutv[nt];
    }

    // h-writes into ALTERNATE buffer at A-row 4*lg
    Anxt[(4 * lg) * ASTR + (n0 + lr)]      = hpk[0];
    Anxt[(4 * lg) * ASTR + (n0 + 16 + lr)] = hpk[1];
    // x_{t+1} into ALTERNATE buffer (waves 6,7)
    if (xstage) Anxt[(4 * ((tid >> 5) & 3)) * ASTR + 256 + (tid & 31)] = f2bf(xval);

    // po partial-reduce: 2 shuffle steps; 4 partials per (row, wave)
    po += __shfl_xor(po, 1, 64);
    po += __shfl_xor(po, 2, 64);
    if ((lr & 3) == 0) out_part[cur][lg][w * 4 + (lr >> 2)] = po;

    wg_barrier_lgkm();  // single per-step barrier, LDS-drain only
  }

  // final output
  if (w == 0 && l < 4) {
    float s = boutv;
#pragma unroll
    for (int ww = 0; ww < 32; ++ww) s += out_part[(T_LEN - 1) & 1][l][ww];
    out[(size_t)(wg * 4 + l) * T_LEN + (T_LEN - 1)] = s;
  }
}

extern "C" void kernel_launch(void* const* d_in, const int* in_sizes, int n_in,
                              void* d_out, int out_size, void* d_ws, size_t ws_size,
                              hipStream_t stream) {
  const float* x    = (const float*)d_in[0];
  const float* c0   = (const float*)d_in[1];
  const float* h0   = (const float*)d_in[2];
  const float* Wi   = (const float*)d_in[3];
  const float* bi   = (const float*)d_in[4];
  const float* Wfx  = (const float*)d_in[5];
  const float* bfx  = (const float*)d_in[6];
  const float* Wfh  = (const float*)d_in[7];
  const float* bfh  = (const float*)d_in[8];
  const float* Wgx  = (const float*)d_in[9];
  const float* bgx  = (const float*)d_in[10];
  const float* Wgh  = (const float*)d_in[11];
  const float* bgh  = (const float*)d_in[12];
  const float* Wox  = (const float*)d_in[13];
  const float* box_ = (const float*)d_in[14];
  const float* Woh  = (const float*)d_in[15];
  const float* boh  = (const float*)d_in[16];
  const float* Wout = (const float*)d_in[17];
  const float* bout = (const float*)d_in[18];

  ealstm_kernel<<<dim3(32), dim3(512), 0, stream>>>(
      x, c0, h0, Wi, bi, Wfx, bfx, Wfh, bfh,
      Wgx, bgx, Wgh, bgh, Wox, box_, Woh, boh, Wout, bout,
      (float*)d_out);
}